// Round 4
// baseline (172.077 us; speedup 1.0000x reference)
//
#include <hip/hip_runtime.h>
#include <math.h>

// contracting REN forward. S=8, N=64, NU=6, NY=5, NH=80, B=524288.
// Outputs: hidden (B,8) then y (B,5), concatenated flat.

constexpr int NH = 80;

// workspace layout (float offsets)
constexpr int WS_DTT  = 0;      // [64][64] j-major: DtT[j*64+i] = Dtilde[i][j]
constexpr int WS_C1F  = 4096;   // [64][8]  C1/Lambda, i-major
constexpr int WS_D12F = 4608;   // [64][6]  calD_12/Lambda, i-major
constexpr int WS_BWF  = 4992;   // [64]     bw/Lambda
constexpr int WS_G1   = 5056;   // [8][8]   Einv@F_
constexpr int WS_G2T  = 5120;   // [64][8]  (Einv@B1) transposed, j-major
constexpr int WS_G3   = 5632;   // [8][6]   Einv@calB_2
constexpr int WS_G4   = 5680;   // [8]      Einv@bx
constexpr int WS_D21T = 5688;   // [64][5]  D21 transposed, j-major
// total 6008 floats ~ 24 KB

__global__ void k_prep(const float* __restrict__ X,
                       const float* __restrict__ calB2,
                       const float* __restrict__ calD12,
                       const float* __restrict__ D21,
                       const float* __restrict__ Y1,
                       const float* __restrict__ bias,
                       float* __restrict__ ws) {
    __shared__ float sX[NH * NH];
    __shared__ float sH[NH * NH];
    __shared__ float sM[8][17];     // Gauss-Jordan [E | I], padded
    __shared__ float sEinv[64];
    __shared__ float srL[64];       // 1/Lambda
    __shared__ int   sPiv;
    int tid = threadIdx.x;

    for (int i = tid; i < NH * NH; i += 256) sX[i] = X[i];
    __syncthreads();

    // H = X^T X + eps*I
    for (int idx = tid; idx < NH * NH; idx += 256) {
        int a = idx / NH, b = idx % NH;
        float acc = (a == b) ? 1e-4f : 0.f;
        for (int k = 0; k < NH; k++) acc += sX[k * NH + a] * sX[k * NH + b];
        sH[idx] = acc;
    }
    __syncthreads();

    if (tid < 64) srL[tid] = 2.0f / sH[(8 + tid) * NH + 8 + tid];  // 1/lam

    // M = [E | I],  E = 0.5*(H11 + calP + Y1)
    if (tid < 128) {
        int r = tid >> 4, c = tid & 15;
        sM[r][c] = (c < 8)
            ? 0.5f * (sH[r * NH + c] + sH[(72 + r) * NH + 72 + c] + Y1[r * 8 + c])
            : ((c - 8 == r) ? 1.f : 0.f);
    }
    __syncthreads();

    // parallel Gauss-Jordan with partial pivoting (all LDS, no scratch)
    for (int p = 0; p < 8; p++) {
        if (tid == 0) {
            int pr = p; float best = fabsf(sM[p][p]);
            for (int r = p + 1; r < 8; r++) {
                float v = fabsf(sM[r][p]);
                if (v > best) { best = v; pr = r; }
            }
            sPiv = pr;
        }
        __syncthreads();
        int pr = sPiv;
        if (pr != p && tid < 16) { float tv = sM[p][tid]; sM[p][tid] = sM[pr][tid]; sM[pr][tid] = tv; }
        __syncthreads();
        if (tid < 16) {               // single wave: all lanes read pivot before any write
            float inv = 1.f / sM[p][p];
            sM[p][tid] *= inv;
        }
        __syncthreads();
        float f = 0.f, pc = 0.f;
        if (tid < 128) { int r = tid >> 4, c = tid & 15; f = sM[r][p]; pc = sM[p][c]; }
        __syncthreads();
        if (tid < 128) { int r = tid >> 4, c = tid & 15; if (r != p) sM[r][c] -= f * pc; }
        __syncthreads();
    }
    if (tid < 64) sEinv[tid] = sM[tid >> 3][8 + (tid & 7)];
    __syncthreads();

    // DtT[j][i] = -H22[i][j]/lam[i] for i>j else 0
    for (int idx = tid; idx < 4096; idx += 256) {
        int j = idx >> 6, i = idx & 63;
        ws[WS_DTT + idx] = (i > j) ? -sH[(8 + i) * NH + 8 + j] * srL[i] : 0.f;
    }
    // C1f[i][s] = -H[8+i][s]/lam[i]
    for (int idx = tid; idx < 512; idx += 256) {
        int i = idx >> 3, s2 = idx & 7;
        ws[WS_C1F + idx] = -sH[(8 + i) * NH + s2] * srL[i];
    }
    // D12f = calD_12/lam
    for (int idx = tid; idx < 384; idx += 256) {
        int i = idx / 6;
        ws[WS_D12F + idx] = calD12[idx] * srL[i];
    }
    if (tid < 64) ws[WS_BWF + tid] = bias[8 + tid] * srL[tid];
    // G1 = Einv @ F_
    if (tid < 64) {
        int a = tid >> 3, s2 = tid & 7; float acc = 0.f;
        for (int k = 0; k < 8; k++) acc += sEinv[a * 8 + k] * sH[(72 + k) * NH + s2];
        ws[WS_G1 + tid] = acc;
    }
    // G2T[j][a] = (Einv @ B1)[a][j]
    for (int idx = tid; idx < 512; idx += 256) {
        int j = idx >> 3, a = idx & 7; float acc = 0.f;
        for (int k = 0; k < 8; k++) acc += sEinv[a * 8 + k] * sH[(72 + k) * NH + 8 + j];
        ws[WS_G2T + idx] = acc;
    }
    // G3 = Einv @ calB_2
    if (tid < 48) {
        int a = tid / 6, c = tid % 6; float acc = 0.f;
        for (int k = 0; k < 8; k++) acc += sEinv[a * 8 + k] * calB2[k * 6 + c];
        ws[WS_G3 + tid] = acc;
    }
    // g4 = Einv @ bx
    if (tid < 8) {
        float acc = 0.f;
        for (int k = 0; k < 8; k++) acc += sEinv[tid * 8 + k] * bias[k];
        ws[WS_G4 + tid] = acc;
    }
    // D21T[j][q] = D21[q][j]
    for (int idx = tid; idx < 320; idx += 256) {
        int j = idx / 5, q = idx % 5;
        ws[WS_D21T + idx] = D21[q * 64 + j];
    }
}

__device__ __forceinline__ float fast_tanh(float x) {
    x = fminf(fmaxf(x, -15.f), 15.f);
    float e = __expf(2.f * x);
    return 1.f - 2.f * __builtin_amdgcn_rcpf(e + 1.f);
}

__global__ __launch_bounds__(256, 3) void k_main(
    const float* __restrict__ xg, const float* __restrict__ ug,
    const float* __restrict__ C2, const float* __restrict__ D22,
    const float* __restrict__ bias, const float* __restrict__ ws,
    float* __restrict__ out, int B)
{
    int t = blockIdx.x * blockDim.x + threadIdx.x;
    int BH = B >> 1;
    if (t >= BH) return;
    const int r0 = t, r1 = t + BH;   // two coalesced halves

    float x0[8], x1[8], u0[6], u1[6];
    {
        const float4* xp0 = reinterpret_cast<const float4*>(xg + (size_t)r0 * 8);
        const float4* xp1 = reinterpret_cast<const float4*>(xg + (size_t)r1 * 8);
        float4 a0 = xp0[0], a1 = xp0[1], b0 = xp1[0], b1 = xp1[1];
        x0[0]=a0.x; x0[1]=a0.y; x0[2]=a0.z; x0[3]=a0.w;
        x0[4]=a1.x; x0[5]=a1.y; x0[6]=a1.z; x0[7]=a1.w;
        x1[0]=b0.x; x1[1]=b0.y; x1[2]=b0.z; x1[3]=b0.w;
        x1[4]=b1.x; x1[5]=b1.y; x1[6]=b1.z; x1[7]=b1.w;
        const float2* up0 = reinterpret_cast<const float2*>(ug + (size_t)r0 * 6);
        const float2* up1 = reinterpret_cast<const float2*>(ug + (size_t)r1 * 6);
        float2 c0 = up0[0], c1 = up0[1], c2 = up0[2];
        float2 d0 = up1[0], d1 = up1[1], d2 = up1[2];
        u0[0]=c0.x; u0[1]=c0.y; u0[2]=c1.x; u0[3]=c1.y; u0[4]=c2.x; u0[5]=c2.y;
        u1[0]=d0.x; u1[1]=d0.y; u1[2]=d1.x; u1[3]=d1.y; u1[4]=d2.x; u1[5]=d2.y;
    }

    const float* C1f  = ws + WS_C1F;
    const float* D12f = ws + WS_D12F;
    const float* bwf  = ws + WS_BWF;
    const float* G1   = ws + WS_G1;
    const float* G3   = ws + WS_G3;
    const float* g4   = ws + WS_G4;

    // v0 (bw, 1/Lambda folded)
    float va[64], vb[64];
    #pragma unroll
    for (int i = 0; i < 64; i++) {
        float A = bwf[i], Bv = bwf[i];
        #pragma unroll
        for (int s2 = 0; s2 < 8; s2++) { float c = C1f[i * 8 + s2]; A += x0[s2] * c; Bv += x1[s2] * c; }
        #pragma unroll
        for (int c2 = 0; c2 < 6; c2++) { float c = D12f[i * 6 + c2]; A += u0[c2] * c; Bv += u1[c2] * c; }
        va[i] = A; vb[i] = Bv;
    }

    // pre-accumulate x/u parts of outputs (frees x,u before the scan)
    float ha[8], hb[8];
    #pragma unroll
    for (int a = 0; a < 8; a++) {
        float A = g4[a], Bv = g4[a];
        #pragma unroll
        for (int s2 = 0; s2 < 8; s2++) { float c = G1[a * 8 + s2]; A += x0[s2] * c; Bv += x1[s2] * c; }
        #pragma unroll
        for (int c2 = 0; c2 < 6; c2++) { float c = G3[a * 6 + c2]; A += u0[c2] * c; Bv += u1[c2] * c; }
        ha[a] = A; hb[a] = Bv;
    }
    float ya[5], yb[5];
    #pragma unroll
    for (int q = 0; q < 5; q++) {
        float base = bias[72 + q];
        float A = base, Bv = base;
        #pragma unroll
        for (int s2 = 0; s2 < 8; s2++) { float c = C2[q * 8 + s2]; A += x0[s2] * c; Bv += x1[s2] * c; }
        #pragma unroll
        for (int c2 = 0; c2 < 6; c2++) { float c = D22[q * 6 + c2]; A += u0[c2] * c; Bv += u1[c2] * c; }
        ya[q] = A; yb[q] = Bv;
    }

    // scatter-form tanh scan with output contributions folded in.
    // All v[i] updates at step j are independent FMAs (no reduction chains).
    #pragma unroll
    for (int j = 0; j < 64; j++) {
        float ta = fast_tanh(va[j]);
        float tb = fast_tanh(vb[j]);
        const float* dj = ws + WS_DTT + j * 64;
        #pragma unroll
        for (int i = j + 1; i < 64; i++) { float d = dj[i]; va[i] += d * ta; vb[i] += d * tb; }
        const float* gj = ws + WS_G2T + j * 8;
        #pragma unroll
        for (int a = 0; a < 8; a++) { float g = gj[a]; ha[a] += g * ta; hb[a] += g * tb; }
        const float* dq = ws + WS_D21T + j * 5;
        #pragma unroll
        for (int q = 0; q < 5; q++) { float d2 = dq[q]; ya[q] += d2 * ta; yb[q] += d2 * tb; }
    }

    // stores
    float4* hp0 = reinterpret_cast<float4*>(out + (size_t)r0 * 8);
    hp0[0] = make_float4(ha[0], ha[1], ha[2], ha[3]);
    hp0[1] = make_float4(ha[4], ha[5], ha[6], ha[7]);
    float4* hp1 = reinterpret_cast<float4*>(out + (size_t)r1 * 8);
    hp1[0] = make_float4(hb[0], hb[1], hb[2], hb[3]);
    hp1[1] = make_float4(hb[4], hb[5], hb[6], hb[7]);

    float* yp0 = out + (size_t)B * 8 + (size_t)r0 * 5;
    float* yp1 = out + (size_t)B * 8 + (size_t)r1 * 5;
    #pragma unroll
    for (int q = 0; q < 5; q++) { yp0[q] = ya[q]; yp1[q] = yb[q]; }
}

extern "C" void kernel_launch(void* const* d_in, const int* in_sizes, int n_in,
                              void* d_out, int out_size, void* d_ws, size_t ws_size,
                              hipStream_t stream) {
    const float* x      = (const float*)d_in[0];
    const float* u      = (const float*)d_in[1];
    const float* X      = (const float*)d_in[2];
    const float* calB2  = (const float*)d_in[3];
    const float* C2     = (const float*)d_in[4];
    const float* calD12 = (const float*)d_in[5];
    const float* D21    = (const float*)d_in[6];
    const float* D22    = (const float*)d_in[7];
    const float* Y1     = (const float*)d_in[8];
    const float* bias   = (const float*)d_in[9];
    float* ws  = (float*)d_ws;
    float* out = (float*)d_out;
    int B = in_sizes[0] / 8;
    int BH = B >> 1;

    k_prep<<<1, 256, 0, stream>>>(X, calB2, calD12, D21, Y1, bias, ws);
    k_main<<<(BH + 255) / 256, 256, 0, stream>>>(x, u, C2, D22, bias, ws, out, B);
}